// Round 1
// baseline (1456.303 us; speedup 1.0000x reference)
//
#include <hip/hip_runtime.h>
#include <hip/hip_bf16.h>

// Problem constants (B=16, N=S=2048, D=256, fp32 in/out).
#define BB 16
#define NN 2048
#define SS 2048
#define DD 256

// ---------------------------------------------------------------------------
// Kernel 1: scores = Q @ K^T  (NT GEMM, both row-major [rows][D])
// 64x64 output tile per 256-thread block, 4x4 micro-tile per thread.
// LDS staged transposed ([d][row], +4 pad) so fragments read as float4.
// ---------------------------------------------------------------------------
__global__ __launch_bounds__(256) void k_scores(const float* __restrict__ Q,
                                                const float* __restrict__ K,
                                                float* __restrict__ out) {
    __shared__ __align__(16) float As[32][68];  // [d][n] for Q tile
    __shared__ __align__(16) float Bs[32][68];  // [d][s] for K tile

    const int b  = blockIdx.z;
    const int n0 = blockIdx.y * 64;
    const int s0 = blockIdx.x * 64;
    const float* Qb = Q + (size_t)b * NN * DD;
    const float* Kb = K + (size_t)b * SS * DD;

    const int t  = threadIdx.x;
    const int tx = t & 15;        // key micro-tile
    const int ty = t >> 4;        // query micro-tile
    const int r  = t >> 3;        // staging row 0..31
    const int c4 = (t & 7) << 2;  // staging d-offset 0..28

    float acc[4][4] = {{0.f}};

    for (int d0 = 0; d0 < DD; d0 += 32) {
        float4 q0 = *(const float4*)(Qb + (size_t)(n0 + r) * DD + d0 + c4);
        float4 q1 = *(const float4*)(Qb + (size_t)(n0 + r + 32) * DD + d0 + c4);
        float4 k0 = *(const float4*)(Kb + (size_t)(s0 + r) * DD + d0 + c4);
        float4 k1 = *(const float4*)(Kb + (size_t)(s0 + r + 32) * DD + d0 + c4);
        __syncthreads();
        As[c4 + 0][r] = q0.x; As[c4 + 1][r] = q0.y; As[c4 + 2][r] = q0.z; As[c4 + 3][r] = q0.w;
        As[c4 + 0][r + 32] = q1.x; As[c4 + 1][r + 32] = q1.y; As[c4 + 2][r + 32] = q1.z; As[c4 + 3][r + 32] = q1.w;
        Bs[c4 + 0][r] = k0.x; Bs[c4 + 1][r] = k0.y; Bs[c4 + 2][r] = k0.z; Bs[c4 + 3][r] = k0.w;
        Bs[c4 + 0][r + 32] = k1.x; Bs[c4 + 1][r + 32] = k1.y; Bs[c4 + 2][r + 32] = k1.z; Bs[c4 + 3][r + 32] = k1.w;
        __syncthreads();
#pragma unroll
        for (int kk = 0; kk < 32; ++kk) {
            float4 av = *(const float4*)&As[kk][ty << 2];
            float4 bv = *(const float4*)&Bs[kk][tx << 2];
            float a0 = av.x, a1 = av.y, a2 = av.z, a3 = av.w;
            float b0 = bv.x, b1 = bv.y, b2 = bv.z, b3 = bv.w;
            acc[0][0] += a0 * b0; acc[0][1] += a0 * b1; acc[0][2] += a0 * b2; acc[0][3] += a0 * b3;
            acc[1][0] += a1 * b0; acc[1][1] += a1 * b1; acc[1][2] += a1 * b2; acc[1][3] += a1 * b3;
            acc[2][0] += a2 * b0; acc[2][1] += a2 * b1; acc[2][2] += a2 * b2; acc[2][3] += a2 * b3;
            acc[3][0] += a3 * b0; acc[3][1] += a3 * b1; acc[3][2] += a3 * b2; acc[3][3] += a3 * b3;
        }
    }

    float* ob = out + (size_t)b * NN * SS;
#pragma unroll
    for (int i = 0; i < 4; ++i) {
        float4 v = make_float4(acc[i][0], acc[i][1], acc[i][2], acc[i][3]);
        *(float4*)(ob + (size_t)(n0 + (ty << 2) + i) * SS + s0 + (tx << 2)) = v;
    }
}

// ---------------------------------------------------------------------------
// Kernel 2: row-wise sparsemax, in-place on the scores (gates region), with a
// duplicate write into the A region. One wave (64 lanes) per row, 32 elems per
// lane in registers; shuffle-only reductions (no barriers).
// tau: bisection on g(tau)=sum(max(z-tau,0))-1 over [zmax-1, zmax], then exact
// refine (boundary ties change nothing: an element equal to tau contributes 0
// and leaves (s-1)/k unchanged).
// ---------------------------------------------------------------------------
__global__ __launch_bounds__(256) void k_sparsemax(float* __restrict__ G,
                                                   float* __restrict__ A) {
    const int t = threadIdx.x;
    const int lane = t & 63;
    const size_t row = (size_t)blockIdx.x * 4 + (t >> 6);
    float* z = G + row * SS;
    float* arow = A + row * SS;

    float v[32];
#pragma unroll
    for (int c = 0; c < 8; ++c) {
        float4 zz = *(const float4*)(z + c * 256 + (lane << 2));
        v[c * 4 + 0] = zz.x; v[c * 4 + 1] = zz.y; v[c * 4 + 2] = zz.z; v[c * 4 + 3] = zz.w;
    }

    // wave max
    float m = v[0];
#pragma unroll
    for (int j = 1; j < 32; ++j) m = fmaxf(m, v[j]);
#pragma unroll
    for (int off = 32; off > 0; off >>= 1) m = fmaxf(m, __shfl_xor(m, off, 64));

    // bisection: g(lo) >= 1 >= g(hi), invariant holds at lo = m-1, hi = m
    float lo = m - 1.0f, hi = m;
    for (int it = 0; it < 26; ++it) {
        float mid = 0.5f * (lo + hi);
        float p = 0.f;
#pragma unroll
        for (int j = 0; j < 32; ++j) p += fmaxf(v[j] - mid, 0.f);
#pragma unroll
        for (int off = 32; off > 0; off >>= 1) p += __shfl_xor(p, off, 64);
        if (p >= 1.0f) lo = mid; else hi = mid;
    }

    // exact refine with support {z > lo}
    float cnt = 0.f, s = 0.f;
#pragma unroll
    for (int j = 0; j < 32; ++j) {
        if (v[j] > lo) { cnt += 1.0f; s += v[j]; }
    }
#pragma unroll
    for (int off = 32; off > 0; off >>= 1) {
        cnt += __shfl_xor(cnt, off, 64);
        s   += __shfl_xor(s, off, 64);
    }
    float tau = (s - 1.0f) / cnt;

#pragma unroll
    for (int c = 0; c < 8; ++c) {
        float4 g;
        g.x = fmaxf(v[c * 4 + 0] - tau, 0.f);
        g.y = fmaxf(v[c * 4 + 1] - tau, 0.f);
        g.z = fmaxf(v[c * 4 + 2] - tau, 0.f);
        g.w = fmaxf(v[c * 4 + 3] - tau, 0.f);
        *(float4*)(z + c * 256 + (lane << 2)) = g;
        *(float4*)(arow + c * 256 + (lane << 2)) = g;
    }
}

// ---------------------------------------------------------------------------
// Kernel 3: V = A @ values  (NN GEMM: A [n][s], values [s][d])
// 64(n) x 64(d) tile per block, contraction chunks of 32 over s.
// A staged transposed ([s][n]); values staged natural ([s][d]).
// ---------------------------------------------------------------------------
__global__ __launch_bounds__(256) void k_pv(const float* __restrict__ A,
                                            const float* __restrict__ Val,
                                            float* __restrict__ out) {
    __shared__ __align__(16) float As[32][68];  // [s][n]
    __shared__ __align__(16) float Vs[32][68];  // [s][d]

    const int b  = blockIdx.z;
    const int n0 = blockIdx.y * 64;
    const int d0 = blockIdx.x * 64;
    const float* Ab = A + (size_t)b * NN * SS;
    const float* Vb = Val + (size_t)b * SS * DD;

    const int t  = threadIdx.x;
    const int tx = t & 15;
    const int ty = t >> 4;
    const int ar  = t >> 3;         // 0..31 (n-row within half-tile)
    const int ac4 = (t & 7) << 2;   // s-offset 0..28
    const int vr  = t >> 4;         // 0..15 (s-row)
    const int vc4 = (t & 15) << 2;  // d-offset 0..60

    float acc[4][4] = {{0.f}};

    for (int s0 = 0; s0 < SS; s0 += 32) {
        float4 a0 = *(const float4*)(Ab + (size_t)(n0 + ar) * SS + s0 + ac4);
        float4 a1 = *(const float4*)(Ab + (size_t)(n0 + ar + 32) * SS + s0 + ac4);
        float4 w0 = *(const float4*)(Vb + (size_t)(s0 + vr) * DD + d0 + vc4);
        float4 w1 = *(const float4*)(Vb + (size_t)(s0 + vr + 16) * DD + d0 + vc4);
        __syncthreads();
        As[ac4 + 0][ar] = a0.x; As[ac4 + 1][ar] = a0.y; As[ac4 + 2][ar] = a0.z; As[ac4 + 3][ar] = a0.w;
        As[ac4 + 0][ar + 32] = a1.x; As[ac4 + 1][ar + 32] = a1.y; As[ac4 + 2][ar + 32] = a1.z; As[ac4 + 3][ar + 32] = a1.w;
        *(float4*)&Vs[vr][vc4] = w0;
        *(float4*)&Vs[vr + 16][vc4] = w1;
        __syncthreads();
#pragma unroll
        for (int kk = 0; kk < 32; ++kk) {
            float4 av = *(const float4*)&As[kk][ty << 2];
            float4 bv = *(const float4*)&Vs[kk][tx << 2];
            float a0v = av.x, a1v = av.y, a2v = av.z, a3v = av.w;
            float b0 = bv.x, b1 = bv.y, b2 = bv.z, b3 = bv.w;
            acc[0][0] += a0v * b0; acc[0][1] += a0v * b1; acc[0][2] += a0v * b2; acc[0][3] += a0v * b3;
            acc[1][0] += a1v * b0; acc[1][1] += a1v * b1; acc[1][2] += a1v * b2; acc[1][3] += a1v * b3;
            acc[2][0] += a2v * b0; acc[2][1] += a2v * b1; acc[2][2] += a2v * b2; acc[2][3] += a2v * b3;
            acc[3][0] += a3v * b0; acc[3][1] += a3v * b1; acc[3][2] += a3v * b2; acc[3][3] += a3v * b3;
        }
    }

    float* ob = out + (size_t)b * NN * DD;
#pragma unroll
    for (int i = 0; i < 4; ++i) {
        float4 v = make_float4(acc[i][0], acc[i][1], acc[i][2], acc[i][3]);
        *(float4*)(ob + (size_t)(n0 + (ty << 2) + i) * DD + d0 + (tx << 2)) = v;
    }
}

extern "C" void kernel_launch(void* const* d_in, const int* in_sizes, int n_in,
                              void* d_out, int out_size, void* d_ws, size_t ws_size,
                              hipStream_t stream) {
    const float* Q = (const float*)d_in[0];
    const float* K = (const float*)d_in[1];
    const float* V = (const float*)d_in[2];

    float* out  = (float*)d_out;
    float* Vout = out;                                   // [B,N,D]
    float* Aout = out + (size_t)BB * NN * DD;            // [B,N,S]
    float* Gout = Aout + (size_t)BB * NN * SS;           // [B,N,S]

    // 1) scores -> gates region
    dim3 g1(SS / 64, NN / 64, BB);
    hipLaunchKernelGGL(k_scores, g1, dim3(256), 0, stream, Q, K, Gout);

    // 2) sparsemax in-place on gates region, duplicate into A region
    hipLaunchKernelGGL(k_sparsemax, dim3((BB * NN) / 4), dim3(256), 0, stream, Gout, Aout);

    // 3) V = A @ values
    dim3 g3(DD / 64, NN / 64, BB);
    hipLaunchKernelGGL(k_pv, g3, dim3(256), 0, stream, Aout, V, Vout);
}

// Round 2
// 881.653 us; speedup vs baseline: 1.6518x; 1.6518x over previous
//
#include <hip/hip_runtime.h>
#include <hip/hip_bf16.h>

// Problem constants (B=16, N=S=2048, D=256, fp32 in/out).
#define BB 16
#define NN 2048
#define SS 2048
#define DD 256
#define EE (BB * NN * DD)  // 8388608 elements per tensor

typedef __bf16 bf16x8 __attribute__((ext_vector_type(8)));
typedef __bf16 bf16x4 __attribute__((ext_vector_type(4)));
typedef float floatx4 __attribute__((ext_vector_type(4)));

__device__ __forceinline__ void async16(const __bf16* g, __bf16* l) {
    __builtin_amdgcn_global_load_lds((__attribute__((address_space(1))) void*)g,
                                     (__attribute__((address_space(3))) void*)l, 16, 0, 0);
}

// ---------------------------------------------------------------------------
// Kernel 0: split Q and K (fp32) into bf16 hi/lo pairs, stashed in the A-output
// region (which sparsemax overwrites later in the same launch).
// stash layout (bf16): Qhi[EE] | Qlo[EE] | Khi[EE] | Klo[EE]  = 67 MB
// ---------------------------------------------------------------------------
__global__ __launch_bounds__(256) void k_convert(const float* __restrict__ Q,
                                                 const float* __restrict__ K,
                                                 __bf16* __restrict__ stash) {
    size_t idx = ((size_t)blockIdx.x * 256 + threadIdx.x) * 4;  // over 2*EE elems
    const float* src;
    __bf16 *dh, *dl;
    size_t off;
    if (idx < (size_t)EE) {
        src = Q; dh = stash; dl = stash + (size_t)EE; off = idx;
    } else {
        src = K; dh = stash + 2 * (size_t)EE; dl = stash + 3 * (size_t)EE; off = idx - (size_t)EE;
    }
    float4 v = *(const float4*)(src + off);
    bf16x4 h, l;
    h.x = (__bf16)v.x; h.y = (__bf16)v.y; h.z = (__bf16)v.z; h.w = (__bf16)v.w;
    l.x = (__bf16)(v.x - (float)h.x);
    l.y = (__bf16)(v.y - (float)h.y);
    l.z = (__bf16)(v.z - (float)h.z);
    l.w = (__bf16)(v.w - (float)h.w);
    *(bf16x4*)(dh + off) = h;
    *(bf16x4*)(dl + off) = l;
}

// ---------------------------------------------------------------------------
// Kernel 1: scores = Q @ K^T via split-bf16 MFMA (hi*hi + hi*lo + lo*hi).
// 128x128 tile / block, 4 waves, each wave 64x64 (4x4 tiles of 16x16x32).
// global_load_lds width=16 staging, m97 2-barrier K-loop.
// ---------------------------------------------------------------------------
__global__ __launch_bounds__(256) void k_scores_mfma(const __bf16* __restrict__ stash,
                                                     float* __restrict__ out) {
    __shared__ __bf16 Qh[128 * 32];
    __shared__ __bf16 Ql[128 * 32];
    __shared__ __bf16 Kh[128 * 32];
    __shared__ __bf16 Kl[128 * 32];

    const __bf16* Qhi = stash;
    const __bf16* Qlo = stash + (size_t)EE;
    const __bf16* Khi = stash + 2 * (size_t)EE;
    const __bf16* Klo = stash + 3 * (size_t)EE;

    const int b  = blockIdx.z;
    const int n0 = blockIdx.y * 128;
    const int s0 = blockIdx.x * 128;

    const int t    = threadIdx.x;
    const int wave = t >> 6;
    const int lane = t & 63;

    // staging: row within 64-row pass, 16B d-chunk
    const int srow = (wave << 4) + (lane >> 2);   // 0..63
    const int sd   = (lane & 3) << 3;             // 0,8,16,24 elems
    const int lds0 = srow * 32 + sd;              // == wave*512 + lane*8
    const size_t qg = (size_t)b * NN * DD + (size_t)(n0 + srow) * DD + sd;
    const size_t kg = (size_t)b * SS * DD + (size_t)(s0 + srow) * DD + sd;

    // fragment read offsets
    const int wy = wave >> 1, wx = wave & 1;
    const int frag = (lane & 15) * 32 + (lane >> 4) * 8;

    floatx4 acc[4][4] = {};

    for (int d0 = 0; d0 < DD; d0 += 32) {
        __syncthreads();
        async16(Qhi + qg + d0,            &Qh[lds0]);
        async16(Qhi + qg + d0 + 64 * DD,  &Qh[lds0 + 2048]);
        async16(Qlo + qg + d0,            &Ql[lds0]);
        async16(Qlo + qg + d0 + 64 * DD,  &Ql[lds0 + 2048]);
        async16(Khi + kg + d0,            &Kh[lds0]);
        async16(Khi + kg + d0 + 64 * DD,  &Kh[lds0 + 2048]);
        async16(Klo + kg + d0,            &Kl[lds0]);
        async16(Klo + kg + d0 + 64 * DD,  &Kl[lds0 + 2048]);
        __syncthreads();

        bf16x8 qh[4], ql[4], kh[4], kl[4];
#pragma unroll
        for (int i = 0; i < 4; ++i) {
            qh[i] = *(const bf16x8*)&Qh[(wy * 64 + i * 16) * 32 + frag];
            ql[i] = *(const bf16x8*)&Ql[(wy * 64 + i * 16) * 32 + frag];
            kh[i] = *(const bf16x8*)&Kh[(wx * 64 + i * 16) * 32 + frag];
            kl[i] = *(const bf16x8*)&Kl[(wx * 64 + i * 16) * 32 + frag];
        }
#pragma unroll
        for (int i = 0; i < 4; ++i)
#pragma unroll
            for (int j = 0; j < 4; ++j) {
                acc[i][j] = __builtin_amdgcn_mfma_f32_16x16x32_bf16(qh[i], kh[j], acc[i][j], 0, 0, 0);
                acc[i][j] = __builtin_amdgcn_mfma_f32_16x16x32_bf16(qh[i], kl[j], acc[i][j], 0, 0, 0);
                acc[i][j] = __builtin_amdgcn_mfma_f32_16x16x32_bf16(ql[i], kh[j], acc[i][j], 0, 0, 0);
            }
    }

    // C/D layout: col = lane&15, row = (lane>>4)*4 + reg
    float* ob = out + (size_t)b * NN * SS;
    const int r0 = n0 + wy * 64 + (lane >> 4) * 4;
    const int c0 = s0 + wx * 64 + (lane & 15);
#pragma unroll
    for (int i = 0; i < 4; ++i)
#pragma unroll
        for (int j = 0; j < 4; ++j)
#pragma unroll
            for (int r = 0; r < 4; ++r)
                ob[(size_t)(r0 + i * 16 + r) * SS + c0 + j * 16] = acc[i][j][r];
}

// ---------------------------------------------------------------------------
// Kernel 2: row-wise sparsemax (unchanged from round 1 — passed).
// ---------------------------------------------------------------------------
__global__ __launch_bounds__(256) void k_sparsemax(float* __restrict__ G,
                                                   float* __restrict__ A) {
    const int t = threadIdx.x;
    const int lane = t & 63;
    const size_t row = (size_t)blockIdx.x * 4 + (t >> 6);
    float* z = G + row * SS;
    float* arow = A + row * SS;

    float v[32];
#pragma unroll
    for (int c = 0; c < 8; ++c) {
        float4 zz = *(const float4*)(z + c * 256 + (lane << 2));
        v[c * 4 + 0] = zz.x; v[c * 4 + 1] = zz.y; v[c * 4 + 2] = zz.z; v[c * 4 + 3] = zz.w;
    }

    float m = v[0];
#pragma unroll
    for (int j = 1; j < 32; ++j) m = fmaxf(m, v[j]);
#pragma unroll
    for (int off = 32; off > 0; off >>= 1) m = fmaxf(m, __shfl_xor(m, off, 64));

    float lo = m - 1.0f, hi = m;
    for (int it = 0; it < 26; ++it) {
        float mid = 0.5f * (lo + hi);
        float p = 0.f;
#pragma unroll
        for (int j = 0; j < 32; ++j) p += fmaxf(v[j] - mid, 0.f);
#pragma unroll
        for (int off = 32; off > 0; off >>= 1) p += __shfl_xor(p, off, 64);
        if (p >= 1.0f) lo = mid; else hi = mid;
    }

    float cnt = 0.f, s = 0.f;
#pragma unroll
    for (int j = 0; j < 32; ++j) {
        if (v[j] > lo) { cnt += 1.0f; s += v[j]; }
    }
#pragma unroll
    for (int off = 32; off > 0; off >>= 1) {
        cnt += __shfl_xor(cnt, off, 64);
        s   += __shfl_xor(s, off, 64);
    }
    float tau = (s - 1.0f) / cnt;

#pragma unroll
    for (int c = 0; c < 8; ++c) {
        float4 g;
        g.x = fmaxf(v[c * 4 + 0] - tau, 0.f);
        g.y = fmaxf(v[c * 4 + 1] - tau, 0.f);
        g.z = fmaxf(v[c * 4 + 2] - tau, 0.f);
        g.w = fmaxf(v[c * 4 + 3] - tau, 0.f);
        *(float4*)(z + c * 256 + (lane << 2)) = g;
        *(float4*)(arow + c * 256 + (lane << 2)) = g;
    }
}

// ---------------------------------------------------------------------------
// Kernel 3: V = A @ values exploiting extreme sparsity of A (support ~1-2/row).
// One wave per output row: ballot-scan the A row for nonzeros, broadcast each
// (s, a) and accumulate a * values[s][:] across lanes (lane holds d = lane*4..+3).
// ---------------------------------------------------------------------------
__global__ __launch_bounds__(256) void k_pv_sparse(const float* __restrict__ A,
                                                   const float* __restrict__ Val,
                                                   float* __restrict__ out) {
    const int t = threadIdx.x;
    const int lane = t & 63;
    const size_t row = (size_t)blockIdx.x * 4 + (t >> 6);  // over B*N
    const int b = (int)(row >> 11);                        // NN = 2048
    const float* arow = A + row * SS;
    const float* vb = Val + (size_t)b * SS * DD;

    float4 acc = make_float4(0.f, 0.f, 0.f, 0.f);

    for (int c = 0; c < 8; ++c) {
        float4 av = *(const float4*)(arow + c * 256 + lane * 4);
#pragma unroll
        for (int q = 0; q < 4; ++q) {
            float a = (q == 0) ? av.x : (q == 1) ? av.y : (q == 2) ? av.z : av.w;
            unsigned long long mask = __ballot(a != 0.0f);
            while (mask) {
                int src = __builtin_ctzll(mask);
                mask &= mask - 1;
                float aa = __shfl(a, src, 64);
                int s = c * 256 + src * 4 + q;
                float4 vv = *(const float4*)(vb + (size_t)s * DD + lane * 4);
                acc.x += aa * vv.x;
                acc.y += aa * vv.y;
                acc.z += aa * vv.z;
                acc.w += aa * vv.w;
            }
        }
    }

    *(float4*)(out + row * DD + lane * 4) = acc;
}

extern "C" void kernel_launch(void* const* d_in, const int* in_sizes, int n_in,
                              void* d_out, int out_size, void* d_ws, size_t ws_size,
                              hipStream_t stream) {
    const float* Q = (const float*)d_in[0];
    const float* K = (const float*)d_in[1];
    const float* V = (const float*)d_in[2];

    float* out  = (float*)d_out;
    float* Vout = out;                                   // [B,N,D]
    float* Aout = out + (size_t)BB * NN * DD;            // [B,N,S]
    float* Gout = Aout + (size_t)BB * NN * SS;           // [B,N,S]

    // 0) split Q,K into bf16 hi/lo stash (lives in Aout region until sparsemax)
    __bf16* stash = (__bf16*)Aout;
    hipLaunchKernelGGL(k_convert, dim3((2 * EE / 4) / 256), dim3(256), 0, stream, Q, K, stash);

    // 1) scores -> gates region (split-bf16 MFMA)
    dim3 g1(SS / 128, NN / 128, BB);
    hipLaunchKernelGGL(k_scores_mfma, g1, dim3(256), 0, stream, stash, Gout);

    // 2) sparsemax in-place on gates region, duplicate into A region
    hipLaunchKernelGGL(k_sparsemax, dim3((BB * NN) / 4), dim3(256), 0, stream, Gout, Aout);

    // 3) V = A @ values (sparse gather)
    hipLaunchKernelGGL(k_pv_sparse, dim3((BB * NN) / 4), dim3(256), 0, stream, Aout, V, Vout);
}

// Round 3
// 772.480 us; speedup vs baseline: 1.8852x; 1.1413x over previous
//
#include <hip/hip_runtime.h>
#include <hip/hip_bf16.h>

// Problem constants (B=16, N=S=2048, D=256, fp32 in/out).
#define BB 16
#define NN 2048
#define SS 2048
#define DD 256
#define EE (BB * NN * DD)  // 8388608 elements per tensor

typedef __bf16 bf16x8 __attribute__((ext_vector_type(8)));
typedef __bf16 bf16x4 __attribute__((ext_vector_type(4)));
typedef float floatx4 __attribute__((ext_vector_type(4)));

__device__ __forceinline__ void async16(const __bf16* g, __bf16* l) {
    __builtin_amdgcn_global_load_lds((__attribute__((address_space(1))) void*)g,
                                     (__attribute__((address_space(3))) void*)l, 16, 0, 0);
}

__device__ __forceinline__ void nt_store4(float* p, float x, float y, float z, float w) {
    floatx4 v = {x, y, z, w};
    __builtin_nontemporal_store(v, (floatx4*)p);
}

// ---------------------------------------------------------------------------
// Kernel 0: split Q and K (fp32) into bf16 hi/lo pairs, stashed in the A-output
// region (which the fused sparsemax kernel overwrites later in the launch).
// stash layout (bf16): Qhi[EE] | Qlo[EE] | Khi[EE] | Klo[EE]  = 67 MB
// ---------------------------------------------------------------------------
__global__ __launch_bounds__(256) void k_convert(const float* __restrict__ Q,
                                                 const float* __restrict__ K,
                                                 __bf16* __restrict__ stash) {
    size_t idx = ((size_t)blockIdx.x * 256 + threadIdx.x) * 4;  // over 2*EE elems
    const float* src;
    __bf16 *dh, *dl;
    size_t off;
    if (idx < (size_t)EE) {
        src = Q; dh = stash; dl = stash + (size_t)EE; off = idx;
    } else {
        src = K; dh = stash + 2 * (size_t)EE; dl = stash + 3 * (size_t)EE; off = idx - (size_t)EE;
    }
    float4 v = *(const float4*)(src + off);
    bf16x4 h, l;
    h.x = (__bf16)v.x; h.y = (__bf16)v.y; h.z = (__bf16)v.z; h.w = (__bf16)v.w;
    l.x = (__bf16)(v.x - (float)h.x);
    l.y = (__bf16)(v.y - (float)h.y);
    l.z = (__bf16)(v.z - (float)h.z);
    l.w = (__bf16)(v.w - (float)h.w);
    *(bf16x4*)(dh + off) = h;
    *(bf16x4*)(dl + off) = l;
}

// ---------------------------------------------------------------------------
// Kernel 1: scores = Q @ K^T via split-bf16 MFMA (hi*hi + hi*lo + lo*hi).
// 128x128 tile / block, 4 waves, each wave 64x64 (4x4 tiles of 16x16x32).
// global_load_lds width=16 staging, m97 2-barrier K-loop.
// ---------------------------------------------------------------------------
__global__ __launch_bounds__(256) void k_scores_mfma(const __bf16* __restrict__ stash,
                                                     float* __restrict__ out) {
    __shared__ __bf16 Qh[128 * 32];
    __shared__ __bf16 Ql[128 * 32];
    __shared__ __bf16 Kh[128 * 32];
    __shared__ __bf16 Kl[128 * 32];

    const __bf16* Qhi = stash;
    const __bf16* Qlo = stash + (size_t)EE;
    const __bf16* Khi = stash + 2 * (size_t)EE;
    const __bf16* Klo = stash + 3 * (size_t)EE;

    const int b  = blockIdx.z;
    const int n0 = blockIdx.y * 128;
    const int s0 = blockIdx.x * 128;

    const int t    = threadIdx.x;
    const int wave = t >> 6;
    const int lane = t & 63;

    // staging: row within 64-row pass, 16B d-chunk
    const int srow = (wave << 4) + (lane >> 2);   // 0..63
    const int sd   = (lane & 3) << 3;             // 0,8,16,24 elems
    const int lds0 = srow * 32 + sd;              // == wave*512 + lane*8
    const size_t qg = (size_t)b * NN * DD + (size_t)(n0 + srow) * DD + sd;
    const size_t kg = (size_t)b * SS * DD + (size_t)(s0 + srow) * DD + sd;

    // fragment read offsets
    const int wy = wave >> 1, wx = wave & 1;
    const int frag = (lane & 15) * 32 + (lane >> 4) * 8;

    floatx4 acc[4][4] = {};

    for (int d0 = 0; d0 < DD; d0 += 32) {
        __syncthreads();
        async16(Qhi + qg + d0,            &Qh[lds0]);
        async16(Qhi + qg + d0 + 64 * DD,  &Qh[lds0 + 2048]);
        async16(Qlo + qg + d0,            &Ql[lds0]);
        async16(Qlo + qg + d0 + 64 * DD,  &Ql[lds0 + 2048]);
        async16(Khi + kg + d0,            &Kh[lds0]);
        async16(Khi + kg + d0 + 64 * DD,  &Kh[lds0 + 2048]);
        async16(Klo + kg + d0,            &Kl[lds0]);
        async16(Klo + kg + d0 + 64 * DD,  &Kl[lds0 + 2048]);
        __syncthreads();

        bf16x8 qh[4], ql[4], kh[4], kl[4];
#pragma unroll
        for (int i = 0; i < 4; ++i) {
            qh[i] = *(const bf16x8*)&Qh[(wy * 64 + i * 16) * 32 + frag];
            ql[i] = *(const bf16x8*)&Ql[(wy * 64 + i * 16) * 32 + frag];
            kh[i] = *(const bf16x8*)&Kh[(wx * 64 + i * 16) * 32 + frag];
            kl[i] = *(const bf16x8*)&Kl[(wx * 64 + i * 16) * 32 + frag];
        }
#pragma unroll
        for (int i = 0; i < 4; ++i)
#pragma unroll
            for (int j = 0; j < 4; ++j) {
                acc[i][j] = __builtin_amdgcn_mfma_f32_16x16x32_bf16(qh[i], kh[j], acc[i][j], 0, 0, 0);
                acc[i][j] = __builtin_amdgcn_mfma_f32_16x16x32_bf16(qh[i], kl[j], acc[i][j], 0, 0, 0);
                acc[i][j] = __builtin_amdgcn_mfma_f32_16x16x32_bf16(ql[i], kh[j], acc[i][j], 0, 0, 0);
            }
    }

    // C/D layout: col = lane&15, row = (lane>>4)*4 + reg
    float* ob = out + (size_t)b * NN * SS;
    const int r0 = n0 + wy * 64 + (lane >> 4) * 4;
    const int c0 = s0 + wx * 64 + (lane & 15);
#pragma unroll
    for (int i = 0; i < 4; ++i)
#pragma unroll
        for (int j = 0; j < 4; ++j)
#pragma unroll
            for (int r = 0; r < 4; ++r)
                ob[(size_t)(r0 + i * 16 + r) * SS + c0 + j * 16] = acc[i][j][r];
}

// ---------------------------------------------------------------------------
// Kernel 2 (fused): row-wise sparsemax + sparse PV. One wave per row, 32 score
// elems per lane in registers. tau: 10 bisection steps to bracket the support,
// then 4 Michelot refines (tau = (sum_{z>tau} z - 1)/k), which converge to the
// EXACT tau (support supersets shrink monotonically; idempotent at fixpoint).
// Gates written to both gates and A regions (nontemporal — never re-read).
// PV done from registers: ballot the nonzeros, broadcast (s, a) via shuffle,
// all 64 lanes accumulate a * values[s][lane*4..+3].
// ---------------------------------------------------------------------------
__global__ __launch_bounds__(256) void k_sparsemax_pv(float* __restrict__ G,
                                                      float* __restrict__ A,
                                                      const float* __restrict__ Val,
                                                      float* __restrict__ Vout) {
    const int t = threadIdx.x;
    const int lane = t & 63;
    const size_t row = (size_t)blockIdx.x * 4 + (t >> 6);  // over B*N
    const int b = (int)(row >> 11);                        // NN = 2048
    float* z = G + row * SS;
    float* arow = A + row * SS;
    const float* vb = Val + (size_t)b * SS * DD;

    float v[32];
#pragma unroll
    for (int c = 0; c < 8; ++c) {
        float4 zz = *(const float4*)(z + c * 256 + (lane << 2));
        v[c * 4 + 0] = zz.x; v[c * 4 + 1] = zz.y; v[c * 4 + 2] = zz.z; v[c * 4 + 3] = zz.w;
    }

    // wave max
    float m = v[0];
#pragma unroll
    for (int j = 1; j < 32; ++j) m = fmaxf(m, v[j]);
#pragma unroll
    for (int off = 32; off > 0; off >>= 1) m = fmaxf(m, __shfl_xor(m, off, 64));

    // bisection to bracket the support: g(lo) >= 1 >= g(hi)
    float lo = m - 1.0f, hi = m;
    for (int it = 0; it < 10; ++it) {
        float mid = 0.5f * (lo + hi);
        float p = 0.f;
#pragma unroll
        for (int j = 0; j < 32; ++j) p += fmaxf(v[j] - mid, 0.f);
#pragma unroll
        for (int off = 32; off > 0; off >>= 1) p += __shfl_xor(p, off, 64);
        if (p >= 1.0f) lo = mid; else hi = mid;
    }

    // Michelot refines: support {z > tau} is a (weak) superset of the true
    // support at every step; tau increases monotonically to the exact value.
    float tau = lo;
#pragma unroll
    for (int it = 0; it < 4; ++it) {
        float cnt = 0.f, s = 0.f;
#pragma unroll
        for (int j = 0; j < 32; ++j) {
            if (v[j] > tau) { cnt += 1.0f; s += v[j]; }
        }
#pragma unroll
        for (int off = 32; off > 0; off >>= 1) {
            cnt += __shfl_xor(cnt, off, 64);
            s   += __shfl_xor(s, off, 64);
        }
        tau = (s - 1.0f) / cnt;
    }

    // gates (kept in registers for PV), dual nontemporal store
    float g[32];
#pragma unroll
    for (int c = 0; c < 8; ++c) {
#pragma unroll
        for (int q = 0; q < 4; ++q) g[c * 4 + q] = fmaxf(v[c * 4 + q] - tau, 0.f);
        nt_store4(z + c * 256 + (lane << 2),    g[c * 4], g[c * 4 + 1], g[c * 4 + 2], g[c * 4 + 3]);
        nt_store4(arow + c * 256 + (lane << 2), g[c * 4], g[c * 4 + 1], g[c * 4 + 2], g[c * 4 + 3]);
    }

    // sparse PV from registers
    float4 acc = make_float4(0.f, 0.f, 0.f, 0.f);
#pragma unroll
    for (int c = 0; c < 8; ++c) {
#pragma unroll
        for (int q = 0; q < 4; ++q) {
            float a = g[c * 4 + q];
            unsigned long long mask = __ballot(a != 0.0f);
            while (mask) {
                int src = __builtin_ctzll(mask);
                mask &= mask - 1;
                float aa = __shfl(a, src, 64);
                int s = c * 256 + src * 4 + q;
                float4 vv = *(const float4*)(vb + (size_t)s * DD + lane * 4);
                acc.x += aa * vv.x;
                acc.y += aa * vv.y;
                acc.z += aa * vv.z;
                acc.w += aa * vv.w;
            }
        }
    }

    nt_store4(Vout + row * DD + lane * 4, acc.x, acc.y, acc.z, acc.w);
}

extern "C" void kernel_launch(void* const* d_in, const int* in_sizes, int n_in,
                              void* d_out, int out_size, void* d_ws, size_t ws_size,
                              hipStream_t stream) {
    const float* Q = (const float*)d_in[0];
    const float* K = (const float*)d_in[1];
    const float* V = (const float*)d_in[2];

    float* out  = (float*)d_out;
    float* Vout = out;                                   // [B,N,D]
    float* Aout = out + (size_t)BB * NN * DD;            // [B,N,S]
    float* Gout = Aout + (size_t)BB * NN * SS;           // [B,N,S]

    // 0) split Q,K into bf16 hi/lo stash (lives in Aout region until sparsemax)
    __bf16* stash = (__bf16*)Aout;
    hipLaunchKernelGGL(k_convert, dim3((2 * EE / 4) / 256), dim3(256), 0, stream, Q, K, stash);

    // 1) scores -> gates region (split-bf16 MFMA)
    dim3 g1(SS / 128, NN / 128, BB);
    hipLaunchKernelGGL(k_scores_mfma, g1, dim3(256), 0, stream, stash, Gout);

    // 2) fused sparsemax + PV: gates in-place, duplicate into A, V out
    hipLaunchKernelGGL(k_sparsemax_pv, dim3((BB * NN) / 4), dim3(256), 0, stream,
                       Gout, Aout, V, Vout);
}